// Round 5
// baseline (587.011 us; speedup 1.0000x reference)
//
#include <hip/hip_runtime.h>
#include <hip/hip_bf16.h>
#include <math.h>

#define N_NODES 4096
#define N_EDGES 16384
#define CLIPD   512
#define HID     1024
#define NH      4
#define OUTD    2048
#define NB      32

typedef __bf16 bf16_t;
typedef bf16_t bf16x8 __attribute__((ext_vector_type(8)));
typedef float f32x4 __attribute__((ext_vector_type(4)));
typedef unsigned short u16x8 __attribute__((ext_vector_type(8)));

static __device__ __forceinline__ float lrelu(float x) { return x >= 0.f ? x : 0.2f * x; }

static __device__ __forceinline__ unsigned short f2bf(float f) {
  union { float f; unsigned int u; } v; v.f = f;
  unsigned int u = v.u;
  unsigned int r = (u + 0x7FFFu + ((u >> 16) & 1u)) >> 16;
  return (unsigned short)r;
}
static __device__ __forceinline__ float bf2f(unsigned short u) {
  union { unsigned int i; float f; } v; v.i = ((unsigned int)u) << 16; return v.f;
}

#define GLDS(g, l) __builtin_amdgcn_global_load_lds( \
    (const __attribute__((address_space(1))) void*)(g), \
    (__attribute__((address_space(3))) void*)(l), 16, 0, 0)

// ---------------------------------------------------------------------------
// prep: ALL weight transposes + ALL attention-vector folds in one kernel.
// ---------------------------------------------------------------------------
__device__ __forceinline__ void stcvt_tile(float (*t)[33], const float* __restrict__ in,
                                           unsigned short* __restrict__ out,
                                           int K1, int N1, int NHH, int h, int bx, int by,
                                           float scale) {
  const int k0 = by * 32, n0 = bx * 32;
  const int tx = threadIdx.x & 31, ty = threadIdx.x >> 5;
#pragma unroll
  for (int i = 0; i < 4; ++i)
    t[ty + 8 * i][tx] = in[(size_t)(k0 + ty + 8 * i) * (NHH * N1) + (size_t)h * N1 + n0 + tx];
  __syncthreads();
#pragma unroll
  for (int i = 0; i < 4; ++i)
    out[(size_t)(n0 + ty + 8 * i) * (NHH * K1) + (size_t)h * K1 + k0 + tx] =
        f2bf(scale * t[tx][ty + 8 * i]);
}

__device__ __forceinline__ void vfold(float (*r1)[NH], float (*r2)[NH],
                                      const float* __restrict__ W,
                                      const float* __restrict__ a1v, const float* __restrict__ a2v,
                                      float* __restrict__ o1, float* __restrict__ o2, int C, int k) {
  const int tid = threadIdx.x;
  const float* row = W + (size_t)k * (NH * C);
  float x1[NH] = {0.f, 0.f, 0.f, 0.f}, x2[NH] = {0.f, 0.f, 0.f, 0.f};
  for (int c = tid; c < C; c += 256) {
    for (int h = 0; h < NH; ++h) {
      float w = row[h * C + c];
      x1[h] += w * a1v[h * C + c];
      x2[h] += w * a2v[h * C + c];
    }
  }
  for (int h = 0; h < NH; ++h)
    for (int o = 32; o > 0; o >>= 1) {
      x1[h] += __shfl_down(x1[h], o);
      x2[h] += __shfl_down(x2[h], o);
    }
  const int wid = tid >> 6, lane = tid & 63;
  if (lane == 0)
    for (int h = 0; h < NH; ++h) { r1[wid][h] = x1[h]; r2[wid][h] = x2[h]; }
  __syncthreads();
  if (tid < NH)
    o1[k * NH + tid] = r1[0][tid] + r1[1][tid] + r1[2][tid] + r1[3][tid];
  else if (o2 != nullptr && tid < 2 * NH) {
    int h = tid - NH;
    o2[k * NH + h] = r2[0][h] + r2[1][h] + r2[2][h] + r2[3][h];
  }
}

__global__ __launch_bounds__(256) void prep_kernel(
    const float* __restrict__ W1, const float* __restrict__ W2,
    const float* __restrict__ gW1, const float* __restrict__ gW2,
    unsigned short* __restrict__ B1t, unsigned short* __restrict__ B2t,
    unsigned short* __restrict__ gW1t, unsigned short* __restrict__ gW2t,
    const float* __restrict__ We1, const float* __restrict__ ae1w,
    const float* __restrict__ We2, const float* __restrict__ ae2w,
    const float* __restrict__ asrc1, const float* __restrict__ adst1,
    const float* __restrict__ asrc2, const float* __restrict__ adst2,
    float* __restrict__ v1, float* __restrict__ v2,
    float* __restrict__ us1, float* __restrict__ ud1,
    float* __restrict__ us2, float* __restrict__ ud2) {
  __shared__ float t[32][33];
  __shared__ float r1[4][NH], r2[4][NH];
  const int id = blockIdx.x;
  if (id < 2048) {                 // W1 stacked 0.25x
    int h = id >> 9, r = id & 511;
    stcvt_tile(t, W1, B1t, CLIPD, HID, NH, h, r & 31, r >> 5, 0.25f);
  } else if (id < 10240) {         // W2 stacked 0.25x
    int r2_ = id - 2048;
    int h = r2_ >> 11, r = r2_ & 2047;
    stcvt_tile(t, W2, B2t, HID, OUTD, NH, h, r & 63, r >> 6, 0.25f);
  } else if (id < 12288) {         // gW1
    int r = id - 10240;
    stcvt_tile(t, gW1, gW1t, OUTD, HID, 1, 0, r & 31, r >> 5, 1.0f);
  } else if (id < 13312) {         // gW2
    int r = id - 12288;
    stcvt_tile(t, gW2, gW2t, HID, HID, 1, 0, r & 31, r >> 5, 1.0f);
  } else {
    int vid = id - 13312;
    if (vid < 512)       vfold(r1, r2, We1, ae1w, ae1w, v1, nullptr, HID, vid);
    else if (vid < 1024) vfold(r1, r2, We2, ae2w, ae2w, v2, nullptr, OUTD, vid - 512);
    else if (vid < 1536) vfold(r1, r2, W1, asrc1, adst1, us1, ud1, HID, vid - 1024);
    else                 vfold(r1, r2, W2, asrc2, adst2, us2, ud2, OUTD, vid - 1536);
  }
}

// ---------------------------------------------------------------------------
// Single-block CSR build: degree count + scan + fill, all in LDS.
// ---------------------------------------------------------------------------
__global__ __launch_bounds__(1024) void csr_kernel(const int* __restrict__ ei,
                                                   int* __restrict__ offs,
                                                   int* __restrict__ csr_src, int* __restrict__ csr_eid) {
  __shared__ int sdeg[N_NODES];
  __shared__ int soffs[N_NODES];
  __shared__ int sscan[1024];
  const int t = threadIdx.x;
  for (int i = t; i < N_NODES; i += 1024) sdeg[i] = 0;
  __syncthreads();
  for (int e = t; e < N_EDGES; e += 1024) atomicAdd(&sdeg[ei[N_EDGES + e]], 1);
  __syncthreads();
  const int d0 = sdeg[4 * t], d1 = sdeg[4 * t + 1], d2 = sdeg[4 * t + 2], d3 = sdeg[4 * t + 3];
  sscan[t] = d0 + d1 + d2 + d3;
  __syncthreads();
  for (int off = 1; off < 1024; off <<= 1) {
    int v = (t >= off) ? sscan[t - off] : 0;
    __syncthreads();
    sscan[t] += v;
    __syncthreads();
  }
  const int base = (t > 0) ? sscan[t - 1] : 0;
  soffs[4 * t] = base;
  soffs[4 * t + 1] = base + d0;
  soffs[4 * t + 2] = base + d0 + d1;
  soffs[4 * t + 3] = base + d0 + d1 + d2;
#pragma unroll
  for (int j = 0; j < 4; ++j) offs[4 * t + j] = soffs[4 * t + j];
  if (t == 1023) offs[N_NODES] = sscan[1023];
  sdeg[4 * t] = 0; sdeg[4 * t + 1] = 0; sdeg[4 * t + 2] = 0; sdeg[4 * t + 3] = 0;
  __syncthreads();
  for (int e = t; e < N_EDGES; e += 1024) {
    int dst = ei[N_EDGES + e];
    int pos = soffs[dst] + atomicAdd(&sdeg[dst], 1);
    csr_src[pos] = ei[e];
    csr_eid[pos] = e;
  }
}

// ---------------------------------------------------------------------------
// aexprep: blocks [0,256) = edge-attr attention terms (ae);
//          blocks [256,1280) = x->bf16 + node dots (xprep)
// ---------------------------------------------------------------------------
__global__ __launch_bounds__(256) void aexprep_kernel(
    const float* __restrict__ ea, const int* __restrict__ ei,
    const float* __restrict__ v1, const float* __restrict__ v2,
    float* __restrict__ ae1, float* __restrict__ ae2,
    float* __restrict__ aesum1, float* __restrict__ aesum2,
    const float* __restrict__ x, const float* __restrict__ us, const float* __restrict__ ud,
    unsigned short* __restrict__ xb, float* __restrict__ as_, float* __restrict__ ad_) {
  __shared__ float4 s0[CLIPD];
  __shared__ float4 s1[CLIPD];
  const int tid = threadIdx.x;
  const int wid = tid >> 6, lane = tid & 63;
  if (blockIdx.x < 256) {
    // ---- ae path ----
    s0[tid] = ((const float4*)v1)[tid];
    s0[tid + 256] = ((const float4*)v1)[tid + 256];
    s1[tid] = ((const float4*)v2)[tid];
    s1[tid + 256] = ((const float4*)v2)[tid + 256];
    __syncthreads();
    for (int i = 0; i < 16; ++i) {
      const int e = blockIdx.x * 64 + wid * 16 + i;
      const float* row = ea + (size_t)e * CLIPD;
      float a1[NH] = {0.f, 0.f, 0.f, 0.f}, a2[NH] = {0.f, 0.f, 0.f, 0.f};
      for (int k = lane; k < CLIPD; k += 64) {
        float xv = row[k];
        float4 w1 = s0[k];
        float4 w2 = s1[k];
        a1[0] += xv * w1.x; a1[1] += xv * w1.y; a1[2] += xv * w1.z; a1[3] += xv * w1.w;
        a2[0] += xv * w2.x; a2[1] += xv * w2.y; a2[2] += xv * w2.z; a2[3] += xv * w2.w;
      }
      for (int h = 0; h < NH; ++h)
        for (int o = 32; o > 0; o >>= 1) {
          a1[h] += __shfl_down(a1[h], o);
          a2[h] += __shfl_down(a2[h], o);
        }
      if (lane == 0) {
        int dst = ei[N_EDGES + e];
        for (int h = 0; h < NH; ++h) {
          ae1[e * NH + h] = a1[h];
          ae2[e * NH + h] = a2[h];
          atomicAdd(&aesum1[dst * NH + h], a1[h]);
          atomicAdd(&aesum2[dst * NH + h], a2[h]);
        }
      }
    }
  } else {
    // ---- xprep path ----
    for (int k = tid; k < CLIPD; k += 256) {
      s0[k] = ((const float4*)us)[k];
      s1[k] = ((const float4*)ud)[k];
    }
    __syncthreads();
    const int n = (blockIdx.x - 256) * 4 + wid;
    const float* row = x + (size_t)n * CLIPD;
    unsigned short* orow = xb + (size_t)n * CLIPD;
    float s[NH] = {0.f, 0.f, 0.f, 0.f}, d[NH] = {0.f, 0.f, 0.f, 0.f};
    for (int q = lane; q < CLIPD / 4; q += 64) {
      float4 xv = ((const float4*)row)[q];
      ushort4 ob;
      ob.x = f2bf(xv.x); ob.y = f2bf(xv.y); ob.z = f2bf(xv.z); ob.w = f2bf(xv.w);
      ((ushort4*)orow)[q] = ob;
      const float* xp = &xv.x;
#pragma unroll
      for (int j = 0; j < 4; ++j) {
        float xs = xp[j];
        float4 u = s0[q * 4 + j], v = s1[q * 4 + j];
        s[0] += xs * u.x; s[1] += xs * u.y; s[2] += xs * u.z; s[3] += xs * u.w;
        d[0] += xs * v.x; d[1] += xs * v.y; d[2] += xs * v.z; d[3] += xs * v.w;
      }
    }
#pragma unroll
    for (int h = 0; h < NH; ++h)
      for (int o = 32; o > 0; o >>= 1) {
        s[h] += __shfl_down(s[h], o);
        d[h] += __shfl_down(d[h], o);
      }
    if (lane == 0)
      for (int h = 0; h < NH; ++h) {
        as_[n * NH + h] = s[h];
        ad_[n * NH + h] = d[h];
      }
  }
}

// layer-2 node dots: bf16 out1 rows, C=1024
__global__ __launch_bounds__(256) void rowdot_o(const unsigned short* __restrict__ rows,
                                                const float* __restrict__ us, const float* __restrict__ ud,
                                                float* __restrict__ as_, float* __restrict__ ad_) {
  __shared__ float4 su[HID], sd[HID];
  const int tid = threadIdx.x;
  for (int k = tid; k < HID; k += 256) {
    su[k] = ((const float4*)us)[k];
    sd[k] = ((const float4*)ud)[k];
  }
  __syncthreads();
  const int wid = tid >> 6, lane = tid & 63;
  const int n = blockIdx.x * 4 + wid;
  const unsigned short* row = rows + (size_t)n * HID;
  float s[NH] = {0.f, 0.f, 0.f, 0.f}, d[NH] = {0.f, 0.f, 0.f, 0.f};
  for (int k2 = lane; k2 < HID / 2; k2 += 64) {
    ushort2 uv = ((const ushort2*)row)[k2];
    float f0 = bf2f(uv.x), f1 = bf2f(uv.y);
    float4 u0 = su[2 * k2], u1 = su[2 * k2 + 1];
    float4 v0 = sd[2 * k2], v1 = sd[2 * k2 + 1];
    s[0] += f0 * u0.x + f1 * u1.x; s[1] += f0 * u0.y + f1 * u1.y;
    s[2] += f0 * u0.z + f1 * u1.z; s[3] += f0 * u0.w + f1 * u1.w;
    d[0] += f0 * v0.x + f1 * v1.x; d[1] += f0 * v0.y + f1 * v1.y;
    d[2] += f0 * v0.z + f1 * v1.z; d[3] += f0 * v0.w + f1 * v1.w;
  }
#pragma unroll
  for (int h = 0; h < NH; ++h)
    for (int o = 32; o > 0; o >>= 1) {
      s[h] += __shfl_down(s[h], o);
      d[h] += __shfl_down(d[h], o);
    }
  if (lane == 0)
    for (int h = 0; h < NH; ++h) {
      as_[n * NH + h] = s[h];
      ad_[n * NH + h] = d[h];
    }
}

// ---------------------------------------------------------------------------
// Wave-per-node aggregation: 4 nodes/block, softmax via 16-lane shfl groups,
// 16 B/lane gathers, no __syncthreads. out[n][h*C+c] layout (head-stacked).
// ---------------------------------------------------------------------------
template<int C>
__global__ __launch_bounds__(256) void aggw_kernel(const unsigned short* __restrict__ src,
                                                   const float* __restrict__ as_, const float* __restrict__ ad_,
                                                   const float* __restrict__ aee, const float* __restrict__ aesum,
                                                   const int* __restrict__ offs, const int* __restrict__ csr_src,
                                                   const int* __restrict__ csr_eid,
                                                   unsigned short* __restrict__ out) {
  constexpr int CPT = C / 64;   // 8 (C=512) or 16 (C=1024)
  const int lane = threadIdx.x & 63;
  const int n = blockIdx.x * 4 + (threadIdx.x >> 6);
  const int off = offs[n];
  const int deg = offs[n + 1] - off;
  const int h = lane >> 4, slot = lane & 15;
  const float4 ad4 = *(const float4*)&ad_[n * NH];
  const float4 as4 = *(const float4*)&as_[n * NH];
  const float4 ae4 = *(const float4*)&aesum[n * NH];
  const float adn = ((const float*)&ad4)[h];
  const float aself = lrelu(((const float*)&as4)[h] + adn +
                            ((const float*)&ae4)[h] / fmaxf((float)deg, 1.f));
  float m = (slot == 0) ? aself : -3.0e38f;
  for (int i = slot; i < deg; i += 16) {
    float a = lrelu(as_[csr_src[off + i] * NH + h] + adn + aee[csr_eid[off + i] * NH + h]);
    m = fmaxf(m, a);
  }
#pragma unroll
  for (int o = 1; o < 16; o <<= 1) m = fmaxf(m, __shfl_xor(m, o));
  float den = (slot == 0) ? __expf(aself - m) : 0.f;
  for (int i = slot; i < deg; i += 16) {
    float a = lrelu(as_[csr_src[off + i] * NH + h] + adn + aee[csr_eid[off + i] * NH + h]);
    den += __expf(a - m);
  }
#pragma unroll
  for (int o = 1; o < 16; o <<= 1) den += __shfl_xor(den, o);
  const float wself_l = __expf(aself - m) / den;
  float mh[NH], dh[NH], wsh[NH];
#pragma unroll
  for (int hh = 0; hh < NH; ++hh) {
    mh[hh] = __shfl(m, hh * 16);
    dh[hh] = 1.0f / __shfl(den, hh * 16);
    wsh[hh] = __shfl(wself_l, hh * 16);
  }
  float acc[NH][CPT];
#pragma unroll
  for (int hh = 0; hh < NH; ++hh)
#pragma unroll
    for (int c = 0; c < CPT; ++c) acc[hh][c] = 0.f;
  for (int i = 0; i < deg; ++i) {
    const int sidx = csr_src[off + i];
    const float4 asv = *(const float4*)&as_[sidx * NH];
    const float4 aev = *(const float4*)&aee[csr_eid[off + i] * NH];
    float w[NH];
#pragma unroll
    for (int hh = 0; hh < NH; ++hh)
      w[hh] = __expf(lrelu(((const float*)&asv)[hh] + ((const float*)&ad4)[hh] +
                           ((const float*)&aev)[hh]) - mh[hh]) * dh[hh];
    const unsigned short* hp = src + (size_t)sidx * C + lane * CPT;
#pragma unroll
    for (int v8 = 0; v8 < CPT / 8; ++v8) {
      u16x8 u = *(const u16x8*)(hp + v8 * 8);
#pragma unroll
      for (int c = 0; c < 8; ++c) {
        float f = bf2f(u[c]);
#pragma unroll
        for (int hh = 0; hh < NH; ++hh) acc[hh][v8 * 8 + c] += w[hh] * f;
      }
    }
  }
  {
    const unsigned short* hp = src + (size_t)n * C + lane * CPT;
#pragma unroll
    for (int v8 = 0; v8 < CPT / 8; ++v8) {
      u16x8 u = *(const u16x8*)(hp + v8 * 8);
#pragma unroll
      for (int c = 0; c < 8; ++c) {
        float f = bf2f(u[c]);
#pragma unroll
        for (int hh = 0; hh < NH; ++hh) acc[hh][v8 * 8 + c] += wsh[hh] * f;
      }
    }
  }
#pragma unroll
  for (int hh = 0; hh < NH; ++hh) {
#pragma unroll
    for (int v8 = 0; v8 < CPT / 8; ++v8) {
      u16x8 o;
#pragma unroll
      for (int c = 0; c < 8; ++c) o[c] = f2bf(acc[hh][v8 * 8 + c]);
      *(u16x8*)&out[((size_t)n * NH + hh) * C + lane * CPT + v8 * 8] = o;
    }
  }
}

// ---------------------------------------------------------------------------
// bf16 MFMA GEMM, m97 structure + XCD swizzle. Tile 128 x BN.
// EPI: bias+prelu. WF: also write fp32. GATE: no C store, epilogue reduces
// v*g3[col] over cols -> atomicAdd gate[row] (gate pre-zeroed).
// ---------------------------------------------------------------------------
template<int EPI, int WF, int BN, int GATE>
__global__ __launch_bounds__(256) void mfma_gemm(const unsigned short* __restrict__ A,
                                                 const unsigned short* __restrict__ Bt,
                                                 unsigned short* __restrict__ C,
                                                 float* __restrict__ Cf,
                                                 int M, int N, int K,
                                                 const float* __restrict__ bias,
                                                 const float* __restrict__ pa,
                                                 const float* __restrict__ g3,
                                                 float* __restrict__ gate) {
  constexpr int NFR = BN / 32;
  __shared__ unsigned short As[128 * 32];
  __shared__ unsigned short Bs[BN * 32];
  const int nwg = gridDim.x * gridDim.y;
  int id = blockIdx.y * gridDim.x + blockIdx.x;
  id = (id & 7) * (nwg >> 3) + (id >> 3);
  const int bx = id % gridDim.x, by = id / gridDim.x;
  const int tid = threadIdx.x;
  const int lane = tid & 63;
  const int w = tid >> 6;
  const int wr = w >> 1, wc = w & 1;
  const int brow = by * 128, bcol = bx * BN;
  const int r0 = tid >> 2;
  const int koff = (tid & 3) * 8;
  const int fr = lane & 15;
  const int fk = (lane >> 4) * 8;
  f32x4 acc[4][NFR] = {};
  for (int kt = 0; kt < K; kt += 32) {
    GLDS(A + (size_t)(brow + r0) * K + kt + koff, &As[tid * 8]);
    GLDS(A + (size_t)(brow + 64 + r0) * K + kt + koff, &As[2048 + tid * 8]);
    GLDS(Bt + (size_t)(bcol + r0) * K + kt + koff, &Bs[tid * 8]);
    if constexpr (BN == 128)
      GLDS(Bt + (size_t)(bcol + 64 + r0) * K + kt + koff, &Bs[2048 + tid * 8]);
    asm volatile("s_waitcnt vmcnt(0)" ::: "memory");
    __syncthreads();
    bf16x8 af[4], bfr[NFR];
#pragma unroll
    for (int mi = 0; mi < 4; ++mi)
      af[mi] = *(const bf16x8*)&As[(wr * 64 + mi * 16 + fr) * 32 + fk];
#pragma unroll
    for (int ni = 0; ni < NFR; ++ni)
      bfr[ni] = *(const bf16x8*)&Bs[(wc * (BN / 2) + ni * 16 + fr) * 32 + fk];
#pragma unroll
    for (int mi = 0; mi < 4; ++mi)
#pragma unroll
      for (int ni = 0; ni < NFR; ++ni)
        acc[mi][ni] = __builtin_amdgcn_mfma_f32_16x16x32_bf16(af[mi], bfr[ni], acc[mi][ni], 0, 0, 0);
    __syncthreads();
  }
  const float ap = EPI ? *pa : 0.f;
  float g3v[NFR];
  if constexpr (GATE) {
#pragma unroll
    for (int ni = 0; ni < NFR; ++ni) g3v[ni] = g3[bcol + wc * (BN / 2) + ni * 16 + fr];
  }
#pragma unroll
  for (int mi = 0; mi < 4; ++mi) {
    const int rb = brow + wr * 64 + mi * 16 + (lane >> 4) * 4;
    if constexpr (GATE) {
#pragma unroll
      for (int r = 0; r < 4; ++r) {
        float p = 0.f;
#pragma unroll
        for (int ni = 0; ni < NFR; ++ni) {
          const int col = bcol + wc * (BN / 2) + ni * 16 + fr;
          float v = acc[mi][ni][r] + bias[col];
          v = v >= 0.f ? v : ap * v;
          p += v * g3v[ni];
        }
#pragma unroll
        for (int o = 1; o < 16; o <<= 1) p += __shfl_xor(p, o);
        if (fr == 0) atomicAdd(&gate[rb + r], p);
      }
    } else {
#pragma unroll
      for (int ni = 0; ni < NFR; ++ni) {
        const int col = bcol + wc * (BN / 2) + ni * 16 + fr;
        float bv = 0.f;
        if (EPI) bv = bias[col];
#pragma unroll
        for (int r = 0; r < 4; ++r) {
          float v = acc[mi][ni][r];
          if (EPI) { v += bv; v = v >= 0.f ? v : ap * v; }
          C[(size_t)(rb + r) * N + col] = f2bf(v);
          if (WF) Cf[(size_t)(rb + r) * N + col] = v;
        }
      }
    }
  }
}

// ---------------------------------------------------------------------------
// Fused per-graph softmax + weighted pool (binary search on sorted batch).
// (gb3 omitted: softmax is invariant to a per-graph constant shift.)
// ---------------------------------------------------------------------------
__global__ __launch_bounds__(256) void pool2_kernel(const float* __restrict__ out2,
                                                    const float* __restrict__ gate,
                                                    const int* __restrict__ batch,
                                                    float* __restrict__ dout) {
  const int b = blockIdx.y;
  const int tid = threadIdx.x;
  const int col = blockIdx.x * 256 + tid;
  int lo = 0, hi = N_NODES;
  while (lo < hi) { int mid = (lo + hi) >> 1; if (batch[mid] < b) lo = mid + 1; else hi = mid; }
  const int s = lo;
  hi = N_NODES;
  while (lo < hi) { int mid = (lo + hi) >> 1; if (batch[mid] < b + 1) lo = mid + 1; else hi = mid; }
  const int e = lo;
  __shared__ float red[4];
  const int wid = tid >> 6, lane = tid & 63;
  float m = -3.0e38f;
  for (int n = s + tid; n < e; n += 256) m = fmaxf(m, gate[n]);
  for (int o = 32; o > 0; o >>= 1) m = fmaxf(m, __shfl_down(m, o));
  if (lane == 0) red[wid] = m;
  __syncthreads();
  m = fmaxf(fmaxf(red[0], red[1]), fmaxf(red[2], red[3]));
  __syncthreads();
  float sum = 0.f;
  for (int n = s + tid; n < e; n += 256) sum += __expf(gate[n] - m);
  for (int o = 32; o > 0; o >>= 1) sum += __shfl_down(sum, o);
  if (lane == 0) red[wid] = sum;
  __syncthreads();
  sum = red[0] + red[1] + red[2] + red[3];
  const float gi = 1.0f / fmaxf(sum, 1e-16f);
  float acc = 0.f;
  for (int n = s; n < e; ++n)
    acc += __expf(gate[n] - m) * gi * out2[(size_t)n * OUTD + col];
  dout[(size_t)b * OUTD + col] = acc;
}

// ---------------------------------------------------------------------------
// Workspace layout
// ---------------------------------------------------------------------------
#define MB(x) ((size_t)(x) * 1048576)
#define WS_XB     MB(0)     // 4 MB   bf16 x [4096][512]
#define WS_B1T    MB(4)     // 4 MB   bf16 stacked 0.25*W1^T [1024][2048]
#define WS_B2T    MB(8)     // 16 MB  bf16 stacked 0.25*W2^T [2048][4096]
#define WS_GW1T   MB(24)    // 4 MB   bf16 gW1^T [1024][2048]
#define WS_GW2T   MB(28)    // 2 MB   bf16 gW2^T [1024][1024]
#define WS_AGGX   MB(30)    // 16 MB  bf16 aggX [4096][2048]
#define WS_OUT1B  MB(46)    // 8 MB   bf16 out1 [4096][1024]
#define WS_AGGO   MB(54)    // 32 MB  bf16 aggO [4096][4096]
#define WS_OUT2F  MB(86)    // 32 MB  fp32 out2 [4096][2048]
#define WS_OUT2B  MB(118)   // 16 MB  bf16 out2
#define WS_GH1B   MB(134)   // 8 MB   bf16 gh1 [4096][1024]
#define WS_SM     MB(142)
#define WS_AES1   (WS_SM + 0)        // 64 KB (zeroed)
#define WS_AES2   (WS_AES1 + 65536)  // 64 KB (zeroed)
#define WS_GATE   (WS_AES2 + 65536)  // 16 KB (zeroed)
#define WS_ZBYTES 147456
#define WS_OFFS   (WS_GATE + 16384)  // int[4097]
#define WS_CSRS   (WS_OFFS + 16640)
#define WS_CSRE   (WS_CSRS + 65536)
#define WS_AS1    (WS_CSRE + 65536)
#define WS_AD1    (WS_AS1 + 65536)
#define WS_AEE1   (WS_AD1 + 65536)
#define WS_AS2    (WS_AEE1 + 262144)
#define WS_AD2    (WS_AS2 + 65536)
#define WS_AEE2   (WS_AD2 + 65536)
#define WS_V1     (WS_AEE2 + 262144)
#define WS_V2     (WS_V1 + 8192)
#define WS_US1    (WS_V2 + 8192)
#define WS_UD1    (WS_US1 + 8192)
#define WS_US2    (WS_UD1 + 8192)
#define WS_UD2    (WS_US2 + 16384)

extern "C" void kernel_launch(void* const* d_in, const int* in_sizes, int n_in,
                              void* d_out, int out_size, void* d_ws, size_t ws_size,
                              hipStream_t stream) {
  const float* x     = (const float*)d_in[0];
  const int*   ei    = (const int*)d_in[1];
  const float* ea    = (const float*)d_in[2];
  const int*   batch = (const int*)d_in[3];
  const float* W1    = (const float*)d_in[4];
  const float* asrc1 = (const float*)d_in[5];
  const float* adst1 = (const float*)d_in[6];
  const float* We1   = (const float*)d_in[7];
  const float* ae1w  = (const float*)d_in[8];
  const float* b1    = (const float*)d_in[9];
  const float* p1    = (const float*)d_in[10];
  const float* W2    = (const float*)d_in[11];
  const float* asrc2 = (const float*)d_in[12];
  const float* adst2 = (const float*)d_in[13];
  const float* We2   = (const float*)d_in[14];
  const float* ae2w  = (const float*)d_in[15];
  const float* b2    = (const float*)d_in[16];
  const float* p2    = (const float*)d_in[17];
  const float* gW1   = (const float*)d_in[18];
  const float* gb1   = (const float*)d_in[19];
  const float* gp1   = (const float*)d_in[20];
  const float* gW2   = (const float*)d_in[21];
  const float* gb2   = (const float*)d_in[22];
  const float* gp2   = (const float*)d_in[23];
  const float* gW3   = (const float*)d_in[24];

  char* ws = (char*)d_ws;
  unsigned short* xb    = (unsigned short*)(ws + WS_XB);
  unsigned short* B1t   = (unsigned short*)(ws + WS_B1T);
  unsigned short* B2t   = (unsigned short*)(ws + WS_B2T);
  unsigned short* gW1t  = (unsigned short*)(ws + WS_GW1T);
  unsigned short* gW2t  = (unsigned short*)(ws + WS_GW2T);
  unsigned short* aggXb = (unsigned short*)(ws + WS_AGGX);
  unsigned short* out1b = (unsigned short*)(ws + WS_OUT1B);
  unsigned short* aggOb = (unsigned short*)(ws + WS_AGGO);
  float*          out2f = (float*)(ws + WS_OUT2F);
  unsigned short* out2b = (unsigned short*)(ws + WS_OUT2B);
  unsigned short* gh1b  = (unsigned short*)(ws + WS_GH1B);
  float* aesum1  = (float*)(ws + WS_AES1);
  float* aesum2  = (float*)(ws + WS_AES2);
  float* gate    = (float*)(ws + WS_GATE);
  int*   offs    = (int*)(ws + WS_OFFS);
  int*   csr_src = (int*)(ws + WS_CSRS);
  int*   csr_eid = (int*)(ws + WS_CSRE);
  float* as1     = (float*)(ws + WS_AS1);
  float* ad1     = (float*)(ws + WS_AD1);
  float* aee1    = (float*)(ws + WS_AEE1);
  float* as2     = (float*)(ws + WS_AS2);
  float* ad2     = (float*)(ws + WS_AD2);
  float* aee2    = (float*)(ws + WS_AEE2);
  float* v1      = (float*)(ws + WS_V1);
  float* v2      = (float*)(ws + WS_V2);
  float* us1     = (float*)(ws + WS_US1);
  float* ud1     = (float*)(ws + WS_UD1);
  float* us2     = (float*)(ws + WS_US2);
  float* ud2     = (float*)(ws + WS_UD2);
  float* dout    = (float*)d_out;

  hipMemsetAsync(ws + WS_AES1, 0, WS_ZBYTES, stream);

  csr_kernel<<<1, 1024, 0, stream>>>(ei, offs, csr_src, csr_eid);
  prep_kernel<<<15872, 256, 0, stream>>>(W1, W2, gW1, gW2, B1t, B2t, gW1t, gW2t,
                                         We1, ae1w, We2, ae2w, asrc1, adst1, asrc2, adst2,
                                         v1, v2, us1, ud1, us2, ud2);
  aexprep_kernel<<<1280, 256, 0, stream>>>(ea, ei, v1, v2, aee1, aee2, aesum1, aesum2,
                                           x, us1, ud1, xb, as1, ad1);

  // layer 1
  aggw_kernel<CLIPD><<<N_NODES / 4, 256, 0, stream>>>(xb, as1, ad1, aee1, aesum1,
                                                      offs, csr_src, csr_eid, aggXb);
  mfma_gemm<1, 0, 64, 0><<<dim3(HID / 64, N_NODES / 128), 256, 0, stream>>>(
      aggXb, B1t, out1b, nullptr, N_NODES, HID, NH * CLIPD, b1, p1, nullptr, nullptr);

  // layer 2
  rowdot_o<<<N_NODES / 4, 256, 0, stream>>>(out1b, us2, ud2, as2, ad2);
  aggw_kernel<HID><<<N_NODES / 4, 256, 0, stream>>>(out1b, as2, ad2, aee2, aesum2,
                                                    offs, csr_src, csr_eid, aggOb);
  mfma_gemm<1, 1, 64, 0><<<dim3(OUTD / 64, N_NODES / 128), 256, 0, stream>>>(
      aggOb, B2t, out2b, out2f, N_NODES, OUTD, NH * HID, b2, p2, nullptr, nullptr);

  // gate MLP (gate3 fused into second GEMM's epilogue)
  mfma_gemm<1, 0, 64, 0><<<dim3(HID / 64, N_NODES / 128), 256, 0, stream>>>(
      out2b, gW1t, gh1b, nullptr, N_NODES, HID, OUTD, gb1, gp1, nullptr, nullptr);
  mfma_gemm<1, 0, 64, 1><<<dim3(HID / 64, N_NODES / 128), 256, 0, stream>>>(
      gh1b, gW2t, nullptr, nullptr, N_NODES, HID, HID, gb2, gp2, gW3, gate);

  // pooling
  pool2_kernel<<<dim3(OUTD / 256, NB), 256, 0, stream>>>(out2f, gate, batch, dout);
}